// Round 2
// baseline (238.063 us; speedup 1.0000x reference)
//
#include <hip/hip_runtime.h>
#include <math.h>

// Problem constants
static constexpr int PB = 32;      // batch
static constexpr int PL = 4096;    // seq len
static constexpr int PC = 64;      // in channels
static constexpr int PD = 128;     // out channels
static constexpr int PK = 2048;    // TOPK = L/2

typedef __attribute__((ext_vector_type(8))) short bf16x8;
typedef __attribute__((ext_vector_type(4))) float f32x4;

#define MFMA_BF16(A, B, C) __builtin_amdgcn_mfma_f32_16x16x32_bf16(A, B, C, 0, 0, 0)

static constexpr int HSTR = 264;   // per-wave histogram stride (264 % 32 = 8 -> copies hit different banks)

__device__ inline short f2bf(float f) {
  unsigned u = __float_as_uint(f);
  u += 0x7FFFu + ((u >> 16) & 1u);   // RNE
  return (short)(u >> 16);
}

// ---------------- kernel 1: scores + xbf + W panels + fused top-K select ----
// Grid = 1024 blocks x 256 threads; block handles 128 consecutive rows
// (batch b = blockIdx>>5). After writing scores, each block tickets
// done[b]; the 32nd finisher runs the radix-select for its batch inside
// this kernel, overlapped with other batches' score computation.
// Blocks 0/1 additionally transform sparse_w/full_w (f32 CxD) into
// fragment-ordered bf16 panels in workspace (consumed by kernels 2/3 --
// the kernel boundary guarantees visibility).
__global__ __launch_bounds__(256) void scores_select_kernel(
    const float* __restrict__ x, const float* __restrict__ score_w,
    const float* __restrict__ score_b, const float* __restrict__ sparse_w,
    const float* __restrict__ full_w, float* __restrict__ scores,
    short* __restrict__ xbf, unsigned* __restrict__ wtfg,
    int* __restrict__ selidx, float* __restrict__ agg,
    unsigned* __restrict__ done) {
  __shared__ unsigned hist4[4 * HSTR];  // per-wave histograms, padded stride
  __shared__ unsigned sbuf[257];
  __shared__ unsigned wsum[4];
  __shared__ unsigned sh_prefix, sh_need;
  __shared__ int sh_last;

  int tid = threadIdx.x;
  int blk = blockIdx.x;
  int b = blk >> 5;                  // 32 blocks per batch

  // W panel transforms (blocks 0 and 1 only; cheap, 16 iters)
  if (blk < 2) {
    const float* w = (blk == 0) ? sparse_w : full_w;
    unsigned* dst = wtfg + blk * 4096;
    for (int i = tid; i < 4096; i += 256) {
      int d = i & 127, cp = i >> 7, c = cp * 2;
      float va = w[(size_t)c * PD + d];
      float vb = w[(size_t)(c + 1) * PD + d];
      unsigned lo = (unsigned short)f2bf(va);
      unsigned hi = (unsigned short)f2bf(vb);
      int t = d >> 4, dl = d & 15, h = c >> 5, cq = (c >> 3) & 3, jp = (c & 7) >> 1;
      dst[(((t * 2 + h) * 4 + cq) * 16 + dl) * 4 + jp] = lo | (hi << 16);
    }
  }

  // ---- scores phase: 128 rows per block, 16 rows per iteration ----
  int r  = tid >> 4;
  int c4 = tid & 15;
  float4 wv = *(const float4*)(score_w + c4 * 4);
  float sb0 = score_b[0];
  #pragma unroll
  for (int it = 0; it < 8; ++it) {
    int row = blk * 128 + it * 16 + r;
    float4 xv = *(const float4*)(x + (size_t)row * PC + c4 * 4);
    short4 xbv;
    xbv.x = f2bf(xv.x); xbv.y = f2bf(xv.y); xbv.z = f2bf(xv.z); xbv.w = f2bf(xv.w);
    *(short4*)(xbf + (size_t)row * PC + c4 * 4) = xbv;
    float v = xv.x * wv.x + xv.y * wv.y + xv.z * wv.z + xv.w * wv.w;
    #pragma unroll
    for (int off = 1; off < 16; off <<= 1) v += __shfl_xor(v, off);
    if (c4 == 0) scores[row] = v + sb0;
  }

  // ---- ticket: last block of this batch runs select ----
  __threadfence();                               // release our stores device-wide
  if (tid == 0) sh_last = (atomicAdd(&done[b], 1u) == 31u);
  __syncthreads();
  if (!sh_last) return;
  __threadfence();                               // acquire: invalidate stale cache

  // ---- select phase (one block per batch, all 256 threads) ----
  int lane = tid & 63;
  int wid  = tid >> 6;
  const float* sc = scores + (size_t)b * PL;

  // stage 16 keys into registers (4 coalesced float4 loads)
  unsigned k[16];
  #pragma unroll
  for (int q = 0; q < 4; ++q) {
    float4 f = *(const float4*)(sc + tid * 16 + q * 4);
    unsigned u0 = __float_as_uint(f.x), u1 = __float_as_uint(f.y);
    unsigned u2 = __float_as_uint(f.z), u3 = __float_as_uint(f.w);
    k[q * 4 + 0] = (u0 & 0x80000000u) ? ~u0 : (u0 | 0x80000000u);
    k[q * 4 + 1] = (u1 & 0x80000000u) ? ~u1 : (u1 | 0x80000000u);
    k[q * 4 + 2] = (u2 & 0x80000000u) ? ~u2 : (u2 | 0x80000000u);
    k[q * 4 + 3] = (u3 & 0x80000000u) ? ~u3 : (u3 | 0x80000000u);
  }

  if (tid == 0) { sh_prefix = 0u; sh_need = (unsigned)PK; sbuf[256] = 0u; }
  // zero agg for this batch (sparse_kernel accumulates into it next)
  if (tid < PD) agg[(size_t)b * PD + tid] = 0.f;

  // 4 radix rounds, MSB first
  for (int rr = 3; rr >= 0; --rr) {
    int shift = rr * 8;
    #pragma unroll
    for (int w = 0; w < 4; ++w) hist4[w * HSTR + tid] = 0u;
    __syncthreads();                      // also publishes sh_prefix/sh_need
    unsigned prefix = sh_prefix;
    unsigned need   = sh_need;
    unsigned maskAbove = (rr == 3) ? 0u : (~0u << (shift + 8));
    unsigned* myhist = &hist4[wid * HSTR];
    #pragma unroll
    for (int j = 0; j < 16; ++j) {
      if ((k[j] & maskAbove) == prefix)
        atomicAdd(&myhist[(k[j] >> shift) & 255u], 1u);
    }
    __syncthreads();
    // merge 4 copies + inclusive suffix sum via wave shfl (bucket = tid)
    unsigned v = hist4[tid] + hist4[HSTR + tid] + hist4[2 * HSTR + tid] + hist4[3 * HSTR + tid];
    #pragma unroll
    for (int off = 1; off < 64; off <<= 1) {
      unsigned t = __shfl_down(v, off);
      if (lane + off < 64) v += t;
    }
    if (lane == 0) wsum[wid] = v;         // sum of this wave's 64 buckets
    __syncthreads();
    unsigned add = 0;
    #pragma unroll
    for (int w = 0; w < 4; ++w) if (w > wid) add += wsum[w];
    sbuf[tid] = v + add;
    __syncthreads();
    // suffix non-increasing; unique boundary: sbuf[d]>=need, sbuf[d+1]<need
    if (sbuf[tid] >= need && sbuf[tid + 1] < need) {
      sh_prefix = prefix | ((unsigned)tid << shift);
      sh_need = need - sbuf[tid + 1];
    }
  }
  __syncthreads();
  unsigned T = sh_prefix;       // K-th largest key
  unsigned needEq = sh_need;    // how many ==T to take (lowest indices)

  // each thread owns 16 contiguous indices (base = tid*16), keys in regs
  int base = tid * 16;
  unsigned ceq = 0;
  #pragma unroll
  for (int j = 0; j < 16; ++j) ceq += (k[j] == T);

  // exclusive prefix scan of eq counts (wave shfl + cross-wave)
  unsigned v1 = ceq;
  #pragma unroll
  for (int off = 1; off < 64; off <<= 1) {
    unsigned t = __shfl_up(v1, off);
    if (lane >= off) v1 += t;
  }
  if (lane == 63) wsum[wid] = v1;
  __syncthreads();
  unsigned add1 = 0;
  #pragma unroll
  for (int w = 0; w < 4; ++w) if (w < wid) add1 += wsum[w];
  unsigned eqbase = v1 + add1 - ceq;
  __syncthreads();                        // protect wsum before reuse

  // count selected in my chunk
  unsigned csel = 0, eqr = eqbase;
  #pragma unroll
  for (int j = 0; j < 16; ++j) {
    if (k[j] > T) csel++;
    else if (k[j] == T) { if (eqr < needEq) csel++; eqr++; }
  }
  unsigned v2 = csel;
  #pragma unroll
  for (int off = 1; off < 64; off <<= 1) {
    unsigned t = __shfl_up(v2, off);
    if (lane >= off) v2 += t;
  }
  if (lane == 63) wsum[wid] = v2;
  __syncthreads();
  unsigned add2 = 0;
  #pragma unroll
  for (int w = 0; w < 4; ++w) if (w < wid) add2 += wsum[w];
  unsigned pos = v2 + add2 - csel;

  // write compacted indices
  eqr = eqbase;
  int* outp = selidx + (size_t)b * PK;
  #pragma unroll
  for (int j = 0; j < 16; ++j) {
    bool sel;
    if (k[j] > T) sel = true;
    else if (k[j] == T) { sel = (eqr < needEq); eqr++; }
    else sel = false;
    if (sel) outp[pos++] = base + j;
  }
}

// ---------------- shared staging: 16 KB fragment-ordered W panel -> LDS ------
__device__ inline void stage_wtf(const unsigned* __restrict__ g, unsigned* lds, int tid) {
  #pragma unroll
  for (int q = 0; q < 4; ++q) {
    uint4 v = *(const uint4*)(g + q * 1024 + tid * 4);
    *(uint4*)(lds + q * 1024 + tid * 4) = v;
  }
}

// ---------------- kernel 2: sparse GEMM + gelu + sum into agg ----------------
// block = 256 = 4 waves; each wave: 32 selected rows (2 groups of 16) x 128
// cols via MFMA. B-fragments reused across both row groups (ds:MFMA = 1:2).
__global__ __launch_bounds__(256, 3) void sparse_kernel(
    const short* __restrict__ xbf, const unsigned* __restrict__ wtfg,
    const float* __restrict__ sparse_b, const int* __restrict__ selidx,
    float* __restrict__ agg) {
  __shared__ unsigned WTf[4096];   // 16 KB
  __shared__ float red[PD];
  int tid = threadIdx.x;
  stage_wtf(wtfg, WTf, tid);
  if (tid < PD) red[tid] = 0.f;
  __syncthreads();

  int lane = tid & 63, wid = tid >> 6;
  int ln = lane & 15, quad = lane >> 4;
  int b  = blockIdx.x >> 4;            // 16 row-blocks of 128 per batch
  int rb = blockIdx.x & 15;
  int j0 = rb * 128 + wid * 32 + ln;   // selected slots j0 and j0+16
  const int* sel = selidx + (size_t)b * PK;
  int r0 = sel[j0], r1 = sel[j0 + 16];

  const short* xb = xbf + (size_t)b * PL * PC;
  const short* p0 = xb + (size_t)r0 * PC + quad * 8;
  const short* p1 = xb + (size_t)r1 * PC + quad * 8;
  bf16x8 a00 = *(const bf16x8*)p0, a01 = *(const bf16x8*)(p0 + 32);
  bf16x8 a10 = *(const bf16x8*)p1, a11 = *(const bf16x8*)(p1 + 32);

  f32x4 acc0[8], acc1[8];
  #pragma unroll
  for (int t = 0; t < 8; ++t) { acc0[t] = (f32x4){0.f,0.f,0.f,0.f}; acc1[t] = (f32x4){0.f,0.f,0.f,0.f}; }

  const short* wb = (const short*)WTf + lane * 8;   // contiguous per-wave reads
  #pragma unroll
  for (int t = 0; t < 8; ++t) {
    bf16x8 b0 = *(const bf16x8*)(wb + (2 * t) * 512);
    bf16x8 b1 = *(const bf16x8*)(wb + (2 * t + 1) * 512);
    acc0[t] = MFMA_BF16(a00, b0, acc0[t]);
    acc0[t] = MFMA_BF16(a01, b1, acc0[t]);
    acc1[t] = MFMA_BF16(a10, b0, acc1[t]);
    acc1[t] = MFMA_BF16(a11, b1, acc1[t]);
  }

  // gelu(feat + bias), sum over this wave's 32 rows per column
  #pragma unroll
  for (int t = 0; t < 8; ++t) {
    float bias = sparse_b[t * 16 + ln];
    float s = 0.f;
    #pragma unroll
    for (int i = 0; i < 4; ++i) {
      float v0 = acc0[t][i] + bias;
      s += 0.5f * v0 * (1.0f + erff(v0 * 0.70710678118654752f));
      float v1 = acc1[t][i] + bias;
      s += 0.5f * v1 * (1.0f + erff(v1 * 0.70710678118654752f));
    }
    s += __shfl_xor(s, 16);
    s += __shfl_xor(s, 32);     // sum over all 32 rows of the wave
    if (quad == 0) atomicAdd(&red[t * 16 + ln], s);
  }
  __syncthreads();
  if (tid < PD) atomicAdd(&agg[(size_t)b * PD + tid], red[tid]);
}

// ---------------- kernel 3: full GEMM + agg + LayerNorm + store -------------
// block = 256 = 4 waves; each wave: 32 rows (2 groups of 16) x 128 cols.
__global__ __launch_bounds__(256, 3) void full_ln_kernel(
    const short* __restrict__ xbf, const unsigned* __restrict__ wtfg,
    const float* __restrict__ full_b, const float* __restrict__ ln_g,
    const float* __restrict__ ln_b, const float* __restrict__ agg,
    float* __restrict__ out) {
  __shared__ unsigned WTf[4096];   // 16 KB
  int tid = threadIdx.x;
  stage_wtf(wtfg, WTf, tid);
  __syncthreads();

  int lane = tid & 63, wid = tid >> 6;
  int ln = lane & 15, quad = lane >> 4;
  int rowbase = blockIdx.x * 128 + wid * 32;   // 32 rows per wave
  int b = rowbase >> 12;                       // L = 4096

  const float invK = 1.0f / (float)PK;
  float bias[8], gg[8], bb[8];
  #pragma unroll
  for (int t = 0; t < 8; ++t) {
    int d = t * 16 + ln;
    bias[t] = full_b[d] + agg[(size_t)b * PD + d] * invK;
    gg[t] = ln_g[d];
    bb[t] = ln_b[d];
  }

  const short* p0 = xbf + (size_t)(rowbase + ln) * PC + quad * 8;
  const short* p1 = xbf + (size_t)(rowbase + 16 + ln) * PC + quad * 8;
  bf16x8 a00 = *(const bf16x8*)p0, a01 = *(const bf16x8*)(p0 + 32);
  bf16x8 a10 = *(const bf16x8*)p1, a11 = *(const bf16x8*)(p1 + 32);

  f32x4 acc0[8], acc1[8];
  #pragma unroll
  for (int t = 0; t < 8; ++t) { acc0[t] = (f32x4){0.f,0.f,0.f,0.f}; acc1[t] = (f32x4){0.f,0.f,0.f,0.f}; }

  const short* wb = (const short*)WTf + lane * 8;
  #pragma unroll
  for (int t = 0; t < 8; ++t) {
    bf16x8 b0 = *(const bf16x8*)(wb + (2 * t) * 512);
    bf16x8 b1 = *(const bf16x8*)(wb + (2 * t + 1) * 512);
    acc0[t] = MFMA_BF16(a00, b0, acc0[t]);
    acc0[t] = MFMA_BF16(a01, b1, acc0[t]);
    acc1[t] = MFMA_BF16(a10, b0, acc1[t]);
    acc1[t] = MFMA_BF16(a11, b1, acc1[t]);
  }

  // h = feat + bias; LayerNorm per row (row = rowbase + goff + quad*4 + i,
  // its 128 cols live on the 16 lanes of this quad x 8 tiles)
#define LN_EPILOGUE(ACC, GOFF) do {                                          \
    float s_[4] = {0.f,0.f,0.f,0.f}, ss_[4] = {0.f,0.f,0.f,0.f};             \
    _Pragma("unroll")                                                        \
    for (int t = 0; t < 8; ++t) {                                            \
      _Pragma("unroll")                                                      \
      for (int i = 0; i < 4; ++i) {                                          \
        float h_ = ACC[t][i] + bias[t];                                      \
        ACC[t][i] = h_;                                                      \
        s_[i] += h_; ss_[i] += h_ * h_;                                      \
      }                                                                      \
    }                                                                        \
    _Pragma("unroll")                                                        \
    for (int i = 0; i < 4; ++i) {                                            \
      _Pragma("unroll")                                                      \
      for (int off = 1; off < 16; off <<= 1) {                               \
        s_[i]  += __shfl_xor(s_[i], off);                                    \
        ss_[i] += __shfl_xor(ss_[i], off);                                   \
      }                                                                      \
    }                                                                        \
    _Pragma("unroll")                                                        \
    for (int i = 0; i < 4; ++i) {                                            \
      float mu_  = s_[i] * (1.0f / 128.0f);                                  \
      float var_ = ss_[i] * (1.0f / 128.0f) - mu_ * mu_;                     \
      float inv_ = rsqrtf(var_ + 1e-5f);                                     \
      int r_ = rowbase + (GOFF) + quad * 4 + i;                              \
      float* op_ = out + (size_t)r_ * PD + ln;                               \
      _Pragma("unroll")                                                      \
      for (int t = 0; t < 8; ++t)                                            \
        op_[t * 16] = (ACC[t][i] - mu_) * inv_ * gg[t] + bb[t];              \
    }                                                                        \
  } while (0)

  LN_EPILOGUE(acc0, 0);
  LN_EPILOGUE(acc1, 16);
#undef LN_EPILOGUE
}

// ---------------- launcher ----------------
extern "C" void kernel_launch(void* const* d_in, const int* in_sizes, int n_in,
                              void* d_out, int out_size, void* d_ws, size_t ws_size,
                              hipStream_t stream) {
  const float* x        = (const float*)d_in[0];
  const float* score_w  = (const float*)d_in[1];
  const float* score_b  = (const float*)d_in[2];
  const float* sparse_w = (const float*)d_in[3];
  const float* sparse_b = (const float*)d_in[4];
  const float* full_w   = (const float*)d_in[5];
  const float* full_b   = (const float*)d_in[6];
  const float* ln_g     = (const float*)d_in[7];
  const float* ln_b     = (const float*)d_in[8];
  float* out = (float*)d_out;

  char* ws = (char*)d_ws;
  float*    scores = (float*)ws;                       // B*L f32      (512 KB)
  int*      selidx = (int*)(ws + (512 << 10));         // B*K i32      (256 KB)
  float*    agg    = (float*)(ws + (768 << 10));       // B*D f32      (16 KB)
  unsigned* wtfg   = (unsigned*)(ws + (784 << 10));    // 2 W panels   (32 KB)
  unsigned* done   = (unsigned*)(ws + (816 << 10));    // B ticket ctrs (128 B)
  short*    xbf    = (short*)(ws + (817 << 10));       // B*L*C bf16   (16 MB)

  hipMemsetAsync(done, 0, PB * sizeof(unsigned), stream);
  scores_select_kernel<<<PB * PL / 128, 256, 0, stream>>>(
      x, score_w, score_b, sparse_w, full_w, scores, xbf, wtfg, selidx, agg, done);
  sparse_kernel<<<PB * (PK / 128), 256, 0, stream>>>(xbf, wtfg, sparse_b, selidx, agg);
  full_ln_kernel<<<PB * PL / 128, 256, 0, stream>>>(xbf, wtfg + 4096, full_b,
                                                    ln_g, ln_b, agg, out);
}

// Round 3
// 146.051 us; speedup vs baseline: 1.6300x; 1.6300x over previous
//
#include <hip/hip_runtime.h>
#include <math.h>

// Problem constants
static constexpr int PB = 32;      // batch
static constexpr int PL = 4096;    // seq len
static constexpr int PC = 64;      // in channels
static constexpr int PD = 128;     // out channels
static constexpr int PK = 2048;    // TOPK = L/2

typedef __attribute__((ext_vector_type(8))) short bf16x8;
typedef __attribute__((ext_vector_type(4))) float f32x4;

#define MFMA_BF16(A, B, C) __builtin_amdgcn_mfma_f32_16x16x32_bf16(A, B, C, 0, 0, 0)

__device__ inline short f2bf(float f) {
  unsigned u = __float_as_uint(f);
  u += 0x7FFFu + ((u >> 16) & 1u);   // RNE
  return (short)(u >> 16);
}

__device__ inline unsigned f2key(float f) {
  unsigned u = __float_as_uint(f);
  return (u & 0x80000000u) ? ~u : (u | 0x80000000u);   // sortable uint
}

// ---------------- kernel 1: scores + xbf + W panels + MSB histogram ---------
// float4 loads (16 B/lane). Block = 256 threads = 128 rows (8 iters of 16).
// While scores are in-register, c4==0 lanes atomicAdd a per-batch 2048-bucket
// (top-11-bit sortable-key) histogram in workspace. Plain device-scope
// atomics only -- NO __threadfence (round-2 lesson: fence storms serialize
// the chip). The select kernel consumes the histogram after the kernel
// boundary (implicit coherence).
// Blocks 0/1 additionally transform sparse_w/full_w (f32 CxD) into
// fragment-ordered bf16 panels in workspace.
__global__ __launch_bounds__(256) void scores_kernel(
    const float* __restrict__ x, const float* __restrict__ score_w,
    const float* __restrict__ score_b, const float* __restrict__ sparse_w,
    const float* __restrict__ full_w, float* __restrict__ scores,
    short* __restrict__ xbf, unsigned* __restrict__ wtfg,
    unsigned* __restrict__ ghist) {
  int tid = threadIdx.x;
  int blk = blockIdx.x;
  int b = blk >> 5;                  // 32 blocks per batch (blocks don't straddle)

  // W panel transforms (blocks 0 and 1 only; 16 iters, overlapped with rest)
  if (blk < 2) {
    const float* w = (blk == 0) ? sparse_w : full_w;
    unsigned* dst = wtfg + blk * 4096;
    for (int i = tid; i < 4096; i += 256) {
      int d = i & 127, cp = i >> 7, c = cp * 2;
      float va = w[(size_t)c * PD + d];
      float vb = w[(size_t)(c + 1) * PD + d];
      unsigned lo = (unsigned short)f2bf(va);
      unsigned hi = (unsigned short)f2bf(vb);
      int t = d >> 4, dl = d & 15, h = c >> 5, cq = (c >> 3) & 3, jp = (c & 7) >> 1;
      dst[(((t * 2 + h) * 4 + cq) * 16 + dl) * 4 + jp] = lo | (hi << 16);
    }
  }

  int r  = tid >> 4;
  int c4 = tid & 15;
  float4 wv = *(const float4*)(score_w + c4 * 4);
  float sb0 = score_b[0];
  unsigned* gh = ghist + (size_t)b * 2048;

  #pragma unroll
  for (int it = 0; it < 8; ++it) {
    int row = blk * 128 + it * 16 + r;
    float4 xv = *(const float4*)(x + (size_t)row * PC + c4 * 4);
    short4 xbv;
    xbv.x = f2bf(xv.x); xbv.y = f2bf(xv.y); xbv.z = f2bf(xv.z); xbv.w = f2bf(xv.w);
    *(short4*)(xbf + (size_t)row * PC + c4 * 4) = xbv;
    float v = xv.x * wv.x + xv.y * wv.y + xv.z * wv.z + xv.w * wv.w;
    #pragma unroll
    for (int off = 1; off < 16; off <<= 1) v += __shfl_xor(v, off);
    if (c4 == 0) {
      float sv = v + sb0;
      scores[row] = sv;
      atomicAdd(&gh[f2key(sv) >> 21], 1u);
    }
  }
}

// ---------------- suffix-scan helper for select (N buckets per thread) ------
// hbuf[k] := #keys in buckets >= k, for k in [0, 256*N]; hbuf[256*N] = 0.
template <int N>
__device__ inline void suffix_scan(const unsigned* cnt, int tid, int lane, int wid,
                                   unsigned* hbuf, unsigned* wsum) {
  unsigned tsum = 0;
  #pragma unroll
  for (int i = 0; i < N; ++i) tsum += cnt[i];
  unsigned v = tsum;
  #pragma unroll
  for (int off = 1; off < 64; off <<= 1) {
    unsigned t = __shfl_down(v, off);
    if (lane + off < 64) v += t;
  }
  if (lane == 0) wsum[wid] = v;      // sum over this wave's threads >= own
  __syncthreads();
  unsigned add = 0;
  #pragma unroll
  for (int w = 0; w < 4; ++w) if (w > wid) add += wsum[w];
  unsigned run = v + add - tsum;     // suffix count starting at thread tid+1
  #pragma unroll
  for (int i = N - 1; i >= 0; --i) { run += cnt[i]; hbuf[tid * N + i] = run; }
  if (tid == 0) hbuf[256 * N] = 0;
  __syncthreads();
}

// ---------------- kernel 2: exact top-K via prebuilt MSB histogram ----------
// one block (256 threads) per batch. Round 1 (top 11 bits) comes prebuilt
// from scores_kernel's global histogram; rounds 2 (11 bits) and 3 (10 bits)
// are cheap LDS-atomic rounds over the few surviving keys. Ties at the
// threshold broken by lowest index (matches lax.top_k). Exact.
__global__ __launch_bounds__(256) void select_kernel(
    const float* __restrict__ scores, const unsigned* __restrict__ ghist,
    int* __restrict__ selidx, float* __restrict__ agg) {
  __shared__ unsigned hbuf[2049];
  __shared__ unsigned wsum[4];
  __shared__ unsigned sh_pfx, sh_need;

  int tid = threadIdx.x;
  int lane = tid & 63;
  int wid  = tid >> 6;
  int b = blockIdx.x;
  const float* sc = scores + (size_t)b * PL;

  // stage 16 keys into registers (4 coalesced float4 loads)
  unsigned k[16];
  #pragma unroll
  for (int q = 0; q < 4; ++q) {
    float4 f = *(const float4*)(sc + tid * 16 + q * 4);
    k[q * 4 + 0] = f2key(f.x);
    k[q * 4 + 1] = f2key(f.y);
    k[q * 4 + 2] = f2key(f.z);
    k[q * 4 + 3] = f2key(f.w);
  }
  if (tid == 0) sh_need = (unsigned)PK;
  // zero agg for this batch (sparse_kernel accumulates into it later)
  if (tid < PD) agg[(size_t)b * PD + tid] = 0.f;

  // ---- round 1: top 11 bits, prebuilt histogram ----
  {
    const unsigned* gh = ghist + (size_t)b * 2048;
    uint4 c0 = *(const uint4*)(gh + tid * 8);
    uint4 c1 = *(const uint4*)(gh + tid * 8 + 4);
    unsigned cnt[8] = {c0.x, c0.y, c0.z, c0.w, c1.x, c1.y, c1.z, c1.w};
    suffix_scan<8>(cnt, tid, lane, wid, hbuf, wsum);
    unsigned need = sh_need;     // ordered by scan's internal syncs
    #pragma unroll
    for (int i = 0; i < 8; ++i) {
      int kk = tid * 8 + i;
      if (hbuf[kk] >= need && hbuf[kk + 1] < need) {
        sh_pfx  = (unsigned)kk << 21;
        sh_need = need - hbuf[kk + 1];
      }
    }
  }

  // ---- round 2: bits [20:10], LDS atomics over surviving keys ----
  {
    #pragma unroll
    for (int i = 0; i < 8; ++i) hbuf[tid * 8 + i] = 0u;
    __syncthreads();                         // publishes sh_pfx/sh_need too
    unsigned pfx = sh_pfx, need = sh_need;
    #pragma unroll
    for (int j = 0; j < 16; ++j) {
      if ((k[j] & 0xFFE00000u) == pfx)
        atomicAdd(&hbuf[(k[j] >> 10) & 2047u], 1u);
    }
    __syncthreads();
    unsigned cnt[8];
    #pragma unroll
    for (int i = 0; i < 8; ++i) cnt[i] = hbuf[tid * 8 + i];
    __syncthreads();
    suffix_scan<8>(cnt, tid, lane, wid, hbuf, wsum);
    #pragma unroll
    for (int i = 0; i < 8; ++i) {
      int kk = tid * 8 + i;
      if (hbuf[kk] >= need && hbuf[kk + 1] < need) {
        sh_pfx  = pfx | ((unsigned)kk << 10);
        sh_need = need - hbuf[kk + 1];
      }
    }
  }

  // ---- round 3: bits [9:0], LDS atomics ----
  {
    #pragma unroll
    for (int i = 0; i < 4; ++i) hbuf[tid * 4 + i] = 0u;
    __syncthreads();
    unsigned pfx = sh_pfx, need = sh_need;
    #pragma unroll
    for (int j = 0; j < 16; ++j) {
      if ((k[j] & 0xFFFFFC00u) == pfx)
        atomicAdd(&hbuf[k[j] & 1023u], 1u);
    }
    __syncthreads();
    unsigned cnt[4];
    #pragma unroll
    for (int i = 0; i < 4; ++i) cnt[i] = hbuf[tid * 4 + i];
    __syncthreads();
    suffix_scan<4>(cnt, tid, lane, wid, hbuf, wsum);
    #pragma unroll
    for (int i = 0; i < 4; ++i) {
      int kk = tid * 4 + i;
      if (hbuf[kk] >= need && hbuf[kk + 1] < need) {
        sh_pfx  = pfx | (unsigned)kk;
        sh_need = need - hbuf[kk + 1];
      }
    }
  }
  __syncthreads();
  unsigned T = sh_pfx;          // K-th largest key
  unsigned needEq = sh_need;    // how many ==T to take (lowest indices)

  // each thread owns 16 contiguous indices (base = tid*16), keys in regs
  int base = tid * 16;
  unsigned ceq = 0;
  #pragma unroll
  for (int j = 0; j < 16; ++j) ceq += (k[j] == T);

  // exclusive prefix scan of eq counts (wave shfl + cross-wave)
  unsigned v1 = ceq;
  #pragma unroll
  for (int off = 1; off < 64; off <<= 1) {
    unsigned t = __shfl_up(v1, off);
    if (lane >= off) v1 += t;
  }
  if (lane == 63) wsum[wid] = v1;
  __syncthreads();
  unsigned add1 = 0;
  #pragma unroll
  for (int w = 0; w < 4; ++w) if (w < wid) add1 += wsum[w];
  unsigned eqbase = v1 + add1 - ceq;
  __syncthreads();                        // protect wsum before reuse

  // count selected in my chunk
  unsigned csel = 0, eqr = eqbase;
  #pragma unroll
  for (int j = 0; j < 16; ++j) {
    if (k[j] > T) csel++;
    else if (k[j] == T) { if (eqr < needEq) csel++; eqr++; }
  }
  unsigned v2 = csel;
  #pragma unroll
  for (int off = 1; off < 64; off <<= 1) {
    unsigned t = __shfl_up(v2, off);
    if (lane >= off) v2 += t;
  }
  if (lane == 63) wsum[wid] = v2;
  __syncthreads();
  unsigned add2 = 0;
  #pragma unroll
  for (int w = 0; w < 4; ++w) if (w < wid) add2 += wsum[w];
  unsigned pos = v2 + add2 - csel;

  // write compacted indices
  eqr = eqbase;
  int* outp = selidx + (size_t)b * PK;
  #pragma unroll
  for (int j = 0; j < 16; ++j) {
    bool sel;
    if (k[j] > T) sel = true;
    else if (k[j] == T) { sel = (eqr < needEq); eqr++; }
    else sel = false;
    if (sel) outp[pos++] = base + j;
  }
}

// ---------------- shared staging: 16 KB fragment-ordered W panel -> LDS ------
__device__ inline void stage_wtf(const unsigned* __restrict__ g, unsigned* lds, int tid) {
  #pragma unroll
  for (int q = 0; q < 4; ++q) {
    uint4 v = *(const uint4*)(g + q * 1024 + tid * 4);
    *(uint4*)(lds + q * 1024 + tid * 4) = v;
  }
}

// ---------------- kernel 3: sparse GEMM + gelu + sum into agg ----------------
// block = 256 = 4 waves; each wave: 32 selected rows (2 groups of 16) x 128
// cols via MFMA. B-fragments reused across both row groups (ds:MFMA = 1:2).
__global__ __launch_bounds__(256, 3) void sparse_kernel(
    const short* __restrict__ xbf, const unsigned* __restrict__ wtfg,
    const float* __restrict__ sparse_b, const int* __restrict__ selidx,
    float* __restrict__ agg) {
  __shared__ unsigned WTf[4096];   // 16 KB
  __shared__ float red[PD];
  int tid = threadIdx.x;
  stage_wtf(wtfg, WTf, tid);
  if (tid < PD) red[tid] = 0.f;
  __syncthreads();

  int lane = tid & 63, wid = tid >> 6;
  int ln = lane & 15, quad = lane >> 4;
  int b  = blockIdx.x >> 4;            // 16 row-blocks of 128 per batch
  int rb = blockIdx.x & 15;
  int j0 = rb * 128 + wid * 32 + ln;   // selected slots j0 and j0+16
  const int* sel = selidx + (size_t)b * PK;
  int r0 = sel[j0], r1 = sel[j0 + 16];

  const short* xb = xbf + (size_t)b * PL * PC;
  const short* p0 = xb + (size_t)r0 * PC + quad * 8;
  const short* p1 = xb + (size_t)r1 * PC + quad * 8;
  bf16x8 a00 = *(const bf16x8*)p0, a01 = *(const bf16x8*)(p0 + 32);
  bf16x8 a10 = *(const bf16x8*)p1, a11 = *(const bf16x8*)(p1 + 32);

  f32x4 acc0[8], acc1[8];
  #pragma unroll
  for (int t = 0; t < 8; ++t) { acc0[t] = (f32x4){0.f,0.f,0.f,0.f}; acc1[t] = (f32x4){0.f,0.f,0.f,0.f}; }

  const short* wb = (const short*)WTf + lane * 8;   // contiguous per-wave reads
  #pragma unroll
  for (int t = 0; t < 8; ++t) {
    bf16x8 b0 = *(const bf16x8*)(wb + (2 * t) * 512);
    bf16x8 b1 = *(const bf16x8*)(wb + (2 * t + 1) * 512);
    acc0[t] = MFMA_BF16(a00, b0, acc0[t]);
    acc0[t] = MFMA_BF16(a01, b1, acc0[t]);
    acc1[t] = MFMA_BF16(a10, b0, acc1[t]);
    acc1[t] = MFMA_BF16(a11, b1, acc1[t]);
  }

  // gelu(feat + bias), sum over this wave's 32 rows per column
  #pragma unroll
  for (int t = 0; t < 8; ++t) {
    float bias = sparse_b[t * 16 + ln];
    float s = 0.f;
    #pragma unroll
    for (int i = 0; i < 4; ++i) {
      float v0 = acc0[t][i] + bias;
      s += 0.5f * v0 * (1.0f + erff(v0 * 0.70710678118654752f));
      float v1 = acc1[t][i] + bias;
      s += 0.5f * v1 * (1.0f + erff(v1 * 0.70710678118654752f));
    }
    s += __shfl_xor(s, 16);
    s += __shfl_xor(s, 32);     // sum over all 32 rows of the wave
    if (quad == 0) atomicAdd(&red[t * 16 + ln], s);
  }
  __syncthreads();
  if (tid < PD) atomicAdd(&agg[(size_t)b * PD + tid], red[tid]);
}

// ---------------- kernel 4: full GEMM + agg + LayerNorm + store -------------
// block = 256 = 4 waves; each wave: 32 rows (2 groups of 16) x 128 cols.
__global__ __launch_bounds__(256, 3) void full_ln_kernel(
    const short* __restrict__ xbf, const unsigned* __restrict__ wtfg,
    const float* __restrict__ full_b, const float* __restrict__ ln_g,
    const float* __restrict__ ln_b, const float* __restrict__ agg,
    float* __restrict__ out) {
  __shared__ unsigned WTf[4096];   // 16 KB
  int tid = threadIdx.x;
  stage_wtf(wtfg, WTf, tid);
  __syncthreads();

  int lane = tid & 63, wid = tid >> 6;
  int ln = lane & 15, quad = lane >> 4;
  int rowbase = blockIdx.x * 128 + wid * 32;   // 32 rows per wave
  int b = rowbase >> 12;                       // L = 4096

  const float invK = 1.0f / (float)PK;
  float bias[8], gg[8], bb[8];
  #pragma unroll
  for (int t = 0; t < 8; ++t) {
    int d = t * 16 + ln;
    bias[t] = full_b[d] + agg[(size_t)b * PD + d] * invK;
    gg[t] = ln_g[d];
    bb[t] = ln_b[d];
  }

  const short* p0 = xbf + (size_t)(rowbase + ln) * PC + quad * 8;
  const short* p1 = xbf + (size_t)(rowbase + 16 + ln) * PC + quad * 8;
  bf16x8 a00 = *(const bf16x8*)p0, a01 = *(const bf16x8*)(p0 + 32);
  bf16x8 a10 = *(const bf16x8*)p1, a11 = *(const bf16x8*)(p1 + 32);

  f32x4 acc0[8], acc1[8];
  #pragma unroll
  for (int t = 0; t < 8; ++t) { acc0[t] = (f32x4){0.f,0.f,0.f,0.f}; acc1[t] = (f32x4){0.f,0.f,0.f,0.f}; }

  const short* wb = (const short*)WTf + lane * 8;
  #pragma unroll
  for (int t = 0; t < 8; ++t) {
    bf16x8 b0 = *(const bf16x8*)(wb + (2 * t) * 512);
    bf16x8 b1 = *(const bf16x8*)(wb + (2 * t + 1) * 512);
    acc0[t] = MFMA_BF16(a00, b0, acc0[t]);
    acc0[t] = MFMA_BF16(a01, b1, acc0[t]);
    acc1[t] = MFMA_BF16(a10, b0, acc1[t]);
    acc1[t] = MFMA_BF16(a11, b1, acc1[t]);
  }

  // h = feat + bias; LayerNorm per row (row = rowbase + goff + quad*4 + i,
  // its 128 cols live on the 16 lanes of this quad x 8 tiles)
#define LN_EPILOGUE(ACC, GOFF) do {                                          \
    float s_[4] = {0.f,0.f,0.f,0.f}, ss_[4] = {0.f,0.f,0.f,0.f};             \
    _Pragma("unroll")                                                        \
    for (int t = 0; t < 8; ++t) {                                            \
      _Pragma("unroll")                                                      \
      for (int i = 0; i < 4; ++i) {                                          \
        float h_ = ACC[t][i] + bias[t];                                      \
        ACC[t][i] = h_;                                                      \
        s_[i] += h_; ss_[i] += h_ * h_;                                      \
      }                                                                      \
    }                                                                        \
    _Pragma("unroll")                                                        \
    for (int i = 0; i < 4; ++i) {                                            \
      _Pragma("unroll")                                                      \
      for (int off = 1; off < 16; off <<= 1) {                               \
        s_[i]  += __shfl_xor(s_[i], off);                                    \
        ss_[i] += __shfl_xor(ss_[i], off);                                   \
      }                                                                      \
    }                                                                        \
    _Pragma("unroll")                                                        \
    for (int i = 0; i < 4; ++i) {                                            \
      float mu_  = s_[i] * (1.0f / 128.0f);                                  \
      float var_ = ss_[i] * (1.0f / 128.0f) - mu_ * mu_;                     \
      float inv_ = rsqrtf(var_ + 1e-5f);                                     \
      int r_ = rowbase + (GOFF) + quad * 4 + i;                              \
      float* op_ = out + (size_t)r_ * PD + ln;                               \
      _Pragma("unroll")                                                      \
      for (int t = 0; t < 8; ++t)                                            \
        op_[t * 16] = (ACC[t][i] - mu_) * inv_ * gg[t] + bb[t];              \
    }                                                                        \
  } while (0)

  LN_EPILOGUE(acc0, 0);
  LN_EPILOGUE(acc1, 16);
#undef LN_EPILOGUE
}

// ---------------- launcher ----------------
extern "C" void kernel_launch(void* const* d_in, const int* in_sizes, int n_in,
                              void* d_out, int out_size, void* d_ws, size_t ws_size,
                              hipStream_t stream) {
  const float* x        = (const float*)d_in[0];
  const float* score_w  = (const float*)d_in[1];
  const float* score_b  = (const float*)d_in[2];
  const float* sparse_w = (const float*)d_in[3];
  const float* sparse_b = (const float*)d_in[4];
  const float* full_w   = (const float*)d_in[5];
  const float* full_b   = (const float*)d_in[6];
  const float* ln_g     = (const float*)d_in[7];
  const float* ln_b     = (const float*)d_in[8];
  float* out = (float*)d_out;

  char* ws = (char*)d_ws;
  float*    scores = (float*)ws;                       // B*L f32        (512 KB)
  int*      selidx = (int*)(ws + (512 << 10));         // B*K i32        (256 KB)
  float*    agg    = (float*)(ws + (768 << 10));       // B*D f32        (16 KB)
  unsigned* wtfg   = (unsigned*)(ws + (784 << 10));    // 2 W panels     (32 KB)
  unsigned* ghist  = (unsigned*)(ws + (816 << 10));    // B*2048 u32     (256 KB)
  short*    xbf    = (short*)(ws + (1072 << 10));      // B*L*C bf16     (16 MB)

  hipMemsetAsync(ghist, 0, (size_t)PB * 2048 * sizeof(unsigned), stream);
  scores_kernel<<<PB * PL / 128, 256, 0, stream>>>(x, score_w, score_b, sparse_w,
                                                   full_w, scores, xbf, wtfg, ghist);
  select_kernel<<<PB, 256, 0, stream>>>(scores, ghist, selidx, agg);
  sparse_kernel<<<PB * (PK / 128), 256, 0, stream>>>(xbf, wtfg, sparse_b, selidx, agg);
  full_ln_kernel<<<PB * PL / 128, 256, 0, stream>>>(xbf, wtfg + 4096, full_b,
                                                    ln_g, ln_b, agg, out);
}

// Round 4
// 131.198 us; speedup vs baseline: 1.8145x; 1.1132x over previous
//
#include <hip/hip_runtime.h>
#include <math.h>

// Problem constants
static constexpr int PB = 32;      // batch
static constexpr int PL = 4096;    // seq len
static constexpr int PC = 64;      // in channels
static constexpr int PD = 128;     // out channels
static constexpr int PK = 2048;    // TOPK = L/2

typedef __attribute__((ext_vector_type(8))) short bf16x8;
typedef __attribute__((ext_vector_type(4))) float f32x4;

#define MFMA_BF16(A, B, C) __builtin_amdgcn_mfma_f32_16x16x32_bf16(A, B, C, 0, 0, 0)

__device__ inline short f2bf(float f) {
  unsigned u = __float_as_uint(f);
  u += 0x7FFFu + ((u >> 16) & 1u);   // RNE
  return (short)(u >> 16);
}

// ---------------- kernel 1: scores (B,L) + x->bf16 copy + W panel transforms --
// float4 loads (16 B/lane). Block = 256 threads = 16 rows.
// Blocks 0/1 additionally transform sparse_w/full_w (f32 CxD) into
// fragment-ordered bf16 panels in workspace; one block per batch zeroes agg.
__global__ __launch_bounds__(256) void scores_kernel(
    const float* __restrict__ x, const float* __restrict__ score_w,
    const float* __restrict__ score_b, const float* __restrict__ sparse_w,
    const float* __restrict__ full_w, float* __restrict__ scores,
    short* __restrict__ xbf, unsigned* __restrict__ wtfg,
    float* __restrict__ agg) {
  int tid = threadIdx.x;

  if (blockIdx.x < 2) {
    const float* w = (blockIdx.x == 0) ? sparse_w : full_w;
    unsigned* dst = wtfg + blockIdx.x * 4096;
    for (int i = tid; i < 4096; i += 256) {
      int d = i & 127, cp = i >> 7, c = cp * 2;
      float va = w[(size_t)c * PD + d];
      float vb = w[(size_t)(c + 1) * PD + d];
      unsigned lo = (unsigned short)f2bf(va);
      unsigned hi = (unsigned short)f2bf(vb);
      int t = d >> 4, dl = d & 15, h = c >> 5, cq = (c >> 3) & 3, jp = (c & 7) >> 1;
      dst[(((t * 2 + h) * 4 + cq) * 16 + dl) * 4 + jp] = lo | (hi << 16);
    }
  }
  // zero agg for batch b = blockIdx>>8 (256 blocks per batch; rb==0 does it).
  // sparse_kernel accumulates into agg only after the kernel boundary.
  if ((blockIdx.x & 255) == 0 && tid < PD)
    agg[(size_t)(blockIdx.x >> 8) * PD + tid] = 0.f;

  int r  = tid >> 4;
  int c4 = tid & 15;
  int row = blockIdx.x * 16 + r;                 // grid covers B*L/16 exactly
  float4 xv = *(const float4*)(x + (size_t)row * PC + c4 * 4);
  float4 wv = *(const float4*)(score_w + c4 * 4);

  // bf16 copy of x (RNE, identical bits to what the GEMM kernels consume)
  short4 xbv;
  xbv.x = f2bf(xv.x); xbv.y = f2bf(xv.y); xbv.z = f2bf(xv.z); xbv.w = f2bf(xv.w);
  *(short4*)(xbf + (size_t)row * PC + c4 * 4) = xbv;

  float v = xv.x * wv.x + xv.y * wv.y + xv.z * wv.z + xv.w * wv.w;
  #pragma unroll
  for (int off = 1; off < 16; off <<= 1) v += __shfl_xor(v, off);
  if (c4 == 0) scores[row] = v + score_b[0];
}

// ---------------- shared staging: 16 KB fragment-ordered W panel -> LDS ------
__device__ inline void stage_wtf(const unsigned* __restrict__ g, unsigned* lds, int tid) {
  #pragma unroll
  for (int q = 0; q < 4; ++q) {
    uint4 v = *(const uint4*)(g + q * 1024 + tid * 4);
    *(uint4*)(lds + q * 1024 + tid * 4) = v;
  }
}

// ---------------- kernel 2: fused top-K select + sparse GEMM + gelu + agg ---
// 512 blocks = 16 per batch. EACH block redundantly runs the exact radix
// select for its batch (keys: 16 VGPRs/thread; deterministic -> identical
// threshold in all 16 blocks), keeps only its own 128 selected slots via the
// global prefix scan, then MFMA-GEMMs those rows. Replaces the 32-block
// select_kernel (latency-bound, serialized) with work overlapped across 512
// resident blocks -- no fences, no global atomics, one less launch boundary.
// Ties at threshold by lowest index (matches lax.top_k). Exact.
__global__ __launch_bounds__(256, 3) void sparse_kernel(
    const short* __restrict__ xbf, const unsigned* __restrict__ wtfg,
    const float* __restrict__ sparse_b, const float* __restrict__ scores,
    float* __restrict__ agg) {
  __shared__ unsigned WTf[4096];      // 16 KB
  __shared__ float red[PD];
  __shared__ unsigned hist4[4 * 256]; // per-wave histograms, 4 KB
  __shared__ unsigned sbuf[257];
  __shared__ unsigned wsum[4];
  __shared__ unsigned sh_prefix, sh_need;
  __shared__ int sel_l[128];          // this block's 128 selected rows

  int tid = threadIdx.x;
  stage_wtf(wtfg, WTf, tid);          // loads in flight during select phase
  if (tid < PD) red[tid] = 0.f;

  int lane = tid & 63, wid = tid >> 6;
  int b  = blockIdx.x >> 4;           // 16 row-blocks of 128 per batch
  int rb = blockIdx.x & 15;
  const float* sc = scores + (size_t)b * PL;

  // ---- select phase (identical in all 16 blocks of this batch) ----
  unsigned k[16];
  #pragma unroll
  for (int q = 0; q < 4; ++q) {
    float4 f = *(const float4*)(sc + tid * 16 + q * 4);
    unsigned u0 = __float_as_uint(f.x), u1 = __float_as_uint(f.y);
    unsigned u2 = __float_as_uint(f.z), u3 = __float_as_uint(f.w);
    k[q * 4 + 0] = (u0 & 0x80000000u) ? ~u0 : (u0 | 0x80000000u);
    k[q * 4 + 1] = (u1 & 0x80000000u) ? ~u1 : (u1 | 0x80000000u);
    k[q * 4 + 2] = (u2 & 0x80000000u) ? ~u2 : (u2 | 0x80000000u);
    k[q * 4 + 3] = (u3 & 0x80000000u) ? ~u3 : (u3 | 0x80000000u);
  }
  if (tid == 0) { sh_prefix = 0u; sh_need = (unsigned)PK; sbuf[256] = 0u; }

  // 4 radix rounds, MSB first
  for (int rr = 3; rr >= 0; --rr) {
    int shift = rr * 8;
    #pragma unroll
    for (int w = 0; w < 4; ++w) hist4[w * 256 + tid] = 0u;
    __syncthreads();                      // also publishes sh_prefix/sh_need
    unsigned prefix = sh_prefix;
    unsigned need   = sh_need;
    unsigned maskAbove = (rr == 3) ? 0u : (~0u << (shift + 8));
    unsigned* myhist = &hist4[wid * 256];
    #pragma unroll
    for (int j = 0; j < 16; ++j) {
      if ((k[j] & maskAbove) == prefix)
        atomicAdd(&myhist[(k[j] >> shift) & 255u], 1u);
    }
    __syncthreads();
    // merge 4 copies + inclusive suffix sum via wave shfl (bucket = tid)
    unsigned v = hist4[tid] + hist4[256 + tid] + hist4[512 + tid] + hist4[768 + tid];
    #pragma unroll
    for (int off = 1; off < 64; off <<= 1) {
      unsigned t = __shfl_down(v, off);
      if (lane + off < 64) v += t;
    }
    if (lane == 0) wsum[wid] = v;         // sum of this wave's 64 buckets
    __syncthreads();
    unsigned add = 0;
    #pragma unroll
    for (int w = 0; w < 4; ++w) if (w > wid) add += wsum[w];
    sbuf[tid] = v + add;
    __syncthreads();
    // suffix non-increasing; unique boundary: sbuf[d]>=need, sbuf[d+1]<need
    if (sbuf[tid] >= need && sbuf[tid + 1] < need) {
      sh_prefix = prefix | ((unsigned)tid << shift);
      sh_need = need - sbuf[tid + 1];
    }
  }
  __syncthreads();
  unsigned T = sh_prefix;       // K-th largest key
  unsigned needEq = sh_need;    // how many ==T to take (lowest indices)

  // each thread owns 16 contiguous indices (base = tid*16), keys in regs
  int base = tid * 16;
  unsigned ceq = 0;
  #pragma unroll
  for (int j = 0; j < 16; ++j) ceq += (k[j] == T);

  // exclusive prefix scan of eq counts (wave shfl + cross-wave)
  unsigned v1 = ceq;
  #pragma unroll
  for (int off = 1; off < 64; off <<= 1) {
    unsigned t = __shfl_up(v1, off);
    if (lane >= off) v1 += t;
  }
  if (lane == 63) wsum[wid] = v1;
  __syncthreads();
  unsigned add1 = 0;
  #pragma unroll
  for (int w = 0; w < 4; ++w) if (w < wid) add1 += wsum[w];
  unsigned eqbase = v1 + add1 - ceq;
  __syncthreads();                        // protect wsum before reuse

  // count selected in my chunk
  unsigned csel = 0, eqr = eqbase;
  #pragma unroll
  for (int j = 0; j < 16; ++j) {
    if (k[j] > T) csel++;
    else if (k[j] == T) { if (eqr < needEq) csel++; eqr++; }
  }
  unsigned v2 = csel;
  #pragma unroll
  for (int off = 1; off < 64; off <<= 1) {
    unsigned t = __shfl_up(v2, off);
    if (lane >= off) v2 += t;
  }
  if (lane == 63) wsum[wid] = v2;
  __syncthreads();
  unsigned add2 = 0;
  #pragma unroll
  for (int w = 0; w < 4; ++w) if (w < wid) add2 += wsum[w];
  unsigned pos = v2 + add2 - csel;

  // keep only this block's slot window [rb*128, rb*128+128)
  int lo = rb * 128;
  eqr = eqbase;
  #pragma unroll
  for (int j = 0; j < 16; ++j) {
    bool sel;
    if (k[j] > T) sel = true;
    else if (k[j] == T) { sel = (eqr < needEq); eqr++; }
    else sel = false;
    if (sel) {
      int p = (int)pos++;
      if (p >= lo && p < lo + 128) sel_l[p - lo] = base + j;
    }
  }
  __syncthreads();                       // sel_l + WTf + red all ready

  // ---- GEMM phase: wave computes 32 selected rows x 128 cols ----
  int ln = lane & 15, quad = lane >> 4;
  int jl = wid * 32 + ln;
  int r0 = sel_l[jl], r1 = sel_l[jl + 16];

  const short* xb = xbf + (size_t)b * PL * PC;
  const short* p0 = xb + (size_t)r0 * PC + quad * 8;
  const short* p1 = xb + (size_t)r1 * PC + quad * 8;
  bf16x8 a00 = *(const bf16x8*)p0, a01 = *(const bf16x8*)(p0 + 32);
  bf16x8 a10 = *(const bf16x8*)p1, a11 = *(const bf16x8*)(p1 + 32);

  f32x4 acc0[8], acc1[8];
  #pragma unroll
  for (int t = 0; t < 8; ++t) { acc0[t] = (f32x4){0.f,0.f,0.f,0.f}; acc1[t] = (f32x4){0.f,0.f,0.f,0.f}; }

  const short* wb = (const short*)WTf + lane * 8;   // contiguous per-wave reads
  #pragma unroll
  for (int t = 0; t < 8; ++t) {
    bf16x8 b0 = *(const bf16x8*)(wb + (2 * t) * 512);
    bf16x8 b1 = *(const bf16x8*)(wb + (2 * t + 1) * 512);
    acc0[t] = MFMA_BF16(a00, b0, acc0[t]);
    acc0[t] = MFMA_BF16(a01, b1, acc0[t]);
    acc1[t] = MFMA_BF16(a10, b0, acc1[t]);
    acc1[t] = MFMA_BF16(a11, b1, acc1[t]);
  }

  // gelu(feat + bias), sum over this wave's 32 rows per column
  #pragma unroll
  for (int t = 0; t < 8; ++t) {
    float bias = sparse_b[t * 16 + ln];
    float s = 0.f;
    #pragma unroll
    for (int i = 0; i < 4; ++i) {
      float v0 = acc0[t][i] + bias;
      s += 0.5f * v0 * (1.0f + erff(v0 * 0.70710678118654752f));
      float v1 = acc1[t][i] + bias;
      s += 0.5f * v1 * (1.0f + erff(v1 * 0.70710678118654752f));
    }
    s += __shfl_xor(s, 16);
    s += __shfl_xor(s, 32);     // sum over all 32 rows of the wave
    if (quad == 0) atomicAdd(&red[t * 16 + ln], s);
  }
  __syncthreads();
  if (tid < PD) atomicAdd(&agg[(size_t)b * PD + tid], red[tid]);
}

// ---------------- kernel 3: full GEMM + agg + LayerNorm + store -------------
// block = 256 = 4 waves; each wave: 32 rows (2 groups of 16) x 128 cols.
__global__ __launch_bounds__(256, 3) void full_ln_kernel(
    const short* __restrict__ xbf, const unsigned* __restrict__ wtfg,
    const float* __restrict__ full_b, const float* __restrict__ ln_g,
    const float* __restrict__ ln_b, const float* __restrict__ agg,
    float* __restrict__ out) {
  __shared__ unsigned WTf[4096];   // 16 KB
  int tid = threadIdx.x;
  stage_wtf(wtfg, WTf, tid);
  __syncthreads();

  int lane = tid & 63, wid = tid >> 6;
  int ln = lane & 15, quad = lane >> 4;
  int rowbase = blockIdx.x * 128 + wid * 32;   // 32 rows per wave
  int b = rowbase >> 12;                       // L = 4096

  const float invK = 1.0f / (float)PK;
  float bias[8], gg[8], bb[8];
  #pragma unroll
  for (int t = 0; t < 8; ++t) {
    int d = t * 16 + ln;
    bias[t] = full_b[d] + agg[(size_t)b * PD + d] * invK;
    gg[t] = ln_g[d];
    bb[t] = ln_b[d];
  }

  const short* p0 = xbf + (size_t)(rowbase + ln) * PC + quad * 8;
  const short* p1 = xbf + (size_t)(rowbase + 16 + ln) * PC + quad * 8;
  bf16x8 a00 = *(const bf16x8*)p0, a01 = *(const bf16x8*)(p0 + 32);
  bf16x8 a10 = *(const bf16x8*)p1, a11 = *(const bf16x8*)(p1 + 32);

  f32x4 acc0[8], acc1[8];
  #pragma unroll
  for (int t = 0; t < 8; ++t) { acc0[t] = (f32x4){0.f,0.f,0.f,0.f}; acc1[t] = (f32x4){0.f,0.f,0.f,0.f}; }

  const short* wb = (const short*)WTf + lane * 8;
  #pragma unroll
  for (int t = 0; t < 8; ++t) {
    bf16x8 b0 = *(const bf16x8*)(wb + (2 * t) * 512);
    bf16x8 b1 = *(const bf16x8*)(wb + (2 * t + 1) * 512);
    acc0[t] = MFMA_BF16(a00, b0, acc0[t]);
    acc0[t] = MFMA_BF16(a01, b1, acc0[t]);
    acc1[t] = MFMA_BF16(a10, b0, acc1[t]);
    acc1[t] = MFMA_BF16(a11, b1, acc1[t]);
  }

  // h = feat + bias; LayerNorm per row (row = rowbase + goff + quad*4 + i,
  // its 128 cols live on the 16 lanes of this quad x 8 tiles)
#define LN_EPILOGUE(ACC, GOFF) do {                                          \
    float s_[4] = {0.f,0.f,0.f,0.f}, ss_[4] = {0.f,0.f,0.f,0.f};             \
    _Pragma("unroll")                                                        \
    for (int t = 0; t < 8; ++t) {                                            \
      _Pragma("unroll")                                                      \
      for (int i = 0; i < 4; ++i) {                                          \
        float h_ = ACC[t][i] + bias[t];                                      \
        ACC[t][i] = h_;                                                      \
        s_[i] += h_; ss_[i] += h_ * h_;                                      \
      }                                                                      \
    }                                                                        \
    _Pragma("unroll")                                                        \
    for (int i = 0; i < 4; ++i) {                                            \
      _Pragma("unroll")                                                      \
      for (int off = 1; off < 16; off <<= 1) {                               \
        s_[i]  += __shfl_xor(s_[i], off);                                    \
        ss_[i] += __shfl_xor(ss_[i], off);                                   \
      }                                                                      \
    }                                                                        \
    _Pragma("unroll")                                                        \
    for (int i = 0; i < 4; ++i) {                                            \
      float mu_  = s_[i] * (1.0f / 128.0f);                                  \
      float var_ = ss_[i] * (1.0f / 128.0f) - mu_ * mu_;                     \
      float inv_ = rsqrtf(var_ + 1e-5f);                                     \
      int r_ = rowbase + (GOFF) + quad * 4 + i;                              \
      float* op_ = out + (size_t)r_ * PD + ln;                               \
      _Pragma("unroll")                                                      \
      for (int t = 0; t < 8; ++t)                                            \
        op_[t * 16] = (ACC[t][i] - mu_) * inv_ * gg[t] + bb[t];              \
    }                                                                        \
  } while (0)

  LN_EPILOGUE(acc0, 0);
  LN_EPILOGUE(acc1, 16);
#undef LN_EPILOGUE
}

// ---------------- launcher ----------------
extern "C" void kernel_launch(void* const* d_in, const int* in_sizes, int n_in,
                              void* d_out, int out_size, void* d_ws, size_t ws_size,
                              hipStream_t stream) {
  const float* x        = (const float*)d_in[0];
  const float* score_w  = (const float*)d_in[1];
  const float* score_b  = (const float*)d_in[2];
  const float* sparse_w = (const float*)d_in[3];
  const float* sparse_b = (const float*)d_in[4];
  const float* full_w   = (const float*)d_in[5];
  const float* full_b   = (const float*)d_in[6];
  const float* ln_g     = (const float*)d_in[7];
  const float* ln_b     = (const float*)d_in[8];
  float* out = (float*)d_out;

  char* ws = (char*)d_ws;
  float*    scores = (float*)ws;                       // B*L f32      (512 KB)
  float*    agg    = (float*)(ws + (512 << 10));       // B*D f32      (16 KB)
  unsigned* wtfg   = (unsigned*)(ws + (528 << 10));    // 2 W panels   (32 KB)
  short*    xbf    = (short*)(ws + (560 << 10));       // B*L*C bf16   (16 MB)

  scores_kernel<<<PB * PL / 16, 256, 0, stream>>>(x, score_w, score_b, sparse_w,
                                                  full_w, scores, xbf, wtfg, agg);
  sparse_kernel<<<PB * (PK / 128), 256, 0, stream>>>(xbf, wtfg, sparse_b, scores, agg);
  full_ln_kernel<<<PB * PL / 128, 256, 0, stream>>>(xbf, wtfg + 4096, full_b,
                                                    ln_g, ln_b, agg, out);
}